// Round 8
// baseline (61.466 us; speedup 1.0000x reference)
//
#include <hip/hip_runtime.h>
#include <hip/hip_bf16.h>
#include <hip/hip_cooperative_groups.h>

namespace cg = cooperative_groups;

// Problem: B=32, C=256, H=W=512, labels in [0,150).
// counts[b] = #unique label values in label[b]; out = mean_b( lse(cls[b]) - cls[b][counts[b]] )

#define B_SAMPLES 32
#define C_CLASSES 256
#define N_PER_SAMPLE (512 * 512)
#define CHUNKS 16                          // blocks per sample
#define PER_CHUNK (N_PER_SAMPLE / CHUNKS)  // 16384 elements
#define NBLK (B_SAMPLES * CHUNKS)          // 512 blocks (2/CU -> trivially co-resident)

__global__ __launch_bounds__(256) void fused_coop_kernel(
    const int* __restrict__ label, const float* __restrict__ cls,
    unsigned long long* __restrict__ masks, float* __restrict__ out) {
    const int t = threadIdx.x;
    const int b = blockIdx.x / CHUNKS;
    const int chunk = blockIdx.x % CHUNKS;

    __shared__ int flag[C_CLASSES];
    flag[t] = 0;
    __syncthreads();

    // ---- Phase 1: per-chunk presence mask -> own ws slot (proven R7 code) ----
    const int4* p = reinterpret_cast<const int4*>(
        label + (long)b * N_PER_SAMPLE + (long)chunk * PER_CHUNK);

    int4 v[16];                      // 16 independent dwordx4 loads in flight
    #pragma unroll
    for (int i = 0; i < 16; ++i) v[i] = p[i * 256 + t];

    #pragma unroll
    for (int i = 0; i < 16; ++i) {
        flag[v[i].x & 255] = 1;      // racy same-value stores: fine
        flag[v[i].y & 255] = 1;
        flag[v[i].z & 255] = 1;
        flag[v[i].w & 255] = 1;
    }
    __syncthreads();

    unsigned long long m = __ballot(flag[t] != 0);
    if ((t & 63) == 0) {
        masks[(unsigned)blockIdx.x * 4 + (t >> 6)] = m;  // own slot, overwrites poison
    }

    // ---- Grid-wide barrier: ordering + cross-XCD visibility ----
    cg::this_grid().sync();

    if (blockIdx.x != 0) return;

    // ---- CE tail, block 0 only (proven R7 ce_kernel code, inlined) ----
    __shared__ int cnt_sh[B_SAMPLES];
    __shared__ float partial[4];

    const int w = t >> 6;
    const int l = t & 63;

    float4 x8[8];
    #pragma unroll
    for (int i = 0; i < 8; ++i) {
        x8[i] = reinterpret_cast<const float4*>(cls)[(w * 8 + i) * 64 + l];
    }

    if (t < 128) {
        const int bb   = t >> 2;           // 0..31
        const int word = t & 3;            // 0..3
        const unsigned long long* base = masks + ((unsigned)(bb * CHUNKS)) * 4 + word;

        unsigned long long acc = 0ull;
        #pragma unroll
        for (int jj = 0; jj < 2; ++jj) {   // 2 batches of 8 independent loads
            const unsigned long long y0 = base[(jj * 8 + 0) * 4];
            const unsigned long long y1 = base[(jj * 8 + 1) * 4];
            const unsigned long long y2 = base[(jj * 8 + 2) * 4];
            const unsigned long long y3 = base[(jj * 8 + 3) * 4];
            const unsigned long long y4 = base[(jj * 8 + 4) * 4];
            const unsigned long long y5 = base[(jj * 8 + 5) * 4];
            const unsigned long long y6 = base[(jj * 8 + 6) * 4];
            const unsigned long long y7 = base[(jj * 8 + 7) * 4];
            acc |= ((y0 | y1) | (y2 | y3)) | ((y4 | y5) | (y6 | y7));
        }

        // Full per-(sample,word) union formed BEFORE popcount.
        int pc = __popcll(acc);
        // Words are disjoint bit-ranges -> popcount sums valid across words.
        pc += __shfl_xor(pc, 1);
        pc += __shfl_xor(pc, 2);
        if ((t & 3) == 0) cnt_sh[t >> 2] = pc;
    }
    __syncthreads();

    float nll = 0.0f;
    #pragma unroll
    for (int i = 0; i < 8; ++i) {
        const int bb = w * 8 + i;
        const float4 x = x8[i];
        float mx = fmaxf(fmaxf(x.x, x.y), fmaxf(x.z, x.w));
        #pragma unroll
        for (int off = 32; off > 0; off >>= 1) mx = fmaxf(mx, __shfl_xor(mx, off));
        float e = expf(x.x - mx) + expf(x.y - mx) + expf(x.z - mx) + expf(x.w - mx);
        #pragma unroll
        for (int off = 32; off > 0; off >>= 1) e += __shfl_xor(e, off);
        const float lse = mx + logf(e);

        const int cnt = cnt_sh[bb];           // wave-uniform
        const int comp = cnt & 3;
        const float cand = (comp == 0) ? x.x : (comp == 1) ? x.y
                         : (comp == 2) ? x.z : x.w;
        const float target = __shfl(cand, cnt >> 2);
        nll += lse - target;
    }

    if (l == 0) partial[w] = nll;
    __syncthreads();
    if (t == 0) out[0] = (partial[0] + partial[1] + partial[2] + partial[3]) / (float)B_SAMPLES;
}

extern "C" void kernel_launch(void* const* d_in, const int* in_sizes, int n_in,
                              void* d_out, int out_size, void* d_ws, size_t ws_size,
                              hipStream_t stream) {
    const int* label = (const int*)d_in[1];
    const float* cls = (const float*)d_in[0];
    float* out = (float*)d_out;
    unsigned long long* masks = (unsigned long long*)d_ws;  // 512 * 4 * 8 = 16 KiB

    void* args[] = { (void*)&label, (void*)&cls, (void*)&masks, (void*)&out };
    hipLaunchCooperativeKernel((void*)fused_coop_kernel,
                               dim3(NBLK), dim3(256), args, 0, stream);
}

// Round 9
// 16.435 us; speedup vs baseline: 3.7399x; 3.7399x over previous
//
#include <hip/hip_runtime.h>
#include <hip/hip_bf16.h>

// Problem: B=32, C=256, H=W=512, labels in [0,150).
// counts[b] = #unique label values in label[b]; out = mean_b( lse(cls[b]) - cls[b][counts[b]] )

#define B_SAMPLES 32
#define C_CLASSES 256
#define N_PER_SAMPLE (512 * 512)
#define CHUNKS 8                           // blocks per sample
#define PER_CHUNK (N_PER_SAMPLE / CHUNKS)  // 32768 elements (128 KB)

// Kernel 1: per-chunk 256-bit presence mask -> own ws slot (no atomics, no init).
// ws layout: u64 masks[B_SAMPLES * CHUNKS][4]
__global__ __launch_bounds__(256) void count_bitmap_kernel(
    const int* __restrict__ label, unsigned long long* __restrict__ masks) {
    const int b = blockIdx.x / CHUNKS;
    const int chunk = blockIdx.x % CHUNKS;
    const int t = threadIdx.x;

    __shared__ int flag[C_CLASSES];
    flag[t] = 0;
    __syncthreads();

    const int4* p = reinterpret_cast<const int4*>(
        label + (long)b * N_PER_SAMPLE + (long)chunk * PER_CHUNK);

    // 2 rounds of 16 independent dwordx4 loads (16 in flight, VGPR-bounded).
    #pragma unroll
    for (int r = 0; r < 2; ++r) {
        int4 v[16];
        #pragma unroll
        for (int i = 0; i < 16; ++i) v[i] = p[(r * 16 + i) * 256 + t];
        #pragma unroll
        for (int i = 0; i < 16; ++i) {
            flag[v[i].x & 255] = 1;      // racy same-value stores: fine
            flag[v[i].y & 255] = 1;
            flag[v[i].z & 255] = 1;
            flag[v[i].w & 255] = 1;
        }
    }
    __syncthreads();

    unsigned long long m = __ballot(flag[t] != 0);
    if ((t & 63) == 0) {
        masks[(unsigned)blockIdx.x * 4 + (t >> 6)] = m;  // unconditional: overwrites poison
    }
}

// Kernel 2: OR-reduce chunk masks -> counts; CE in registers.
__global__ __launch_bounds__(256) void ce_kernel(
    const float* __restrict__ cls,
    const unsigned long long* __restrict__ masks,
    float* __restrict__ out) {
    const int t = threadIdx.x;
    const int w = t >> 6;
    const int l = t & 63;

    __shared__ int cnt_sh[B_SAMPLES];
    __shared__ float partial[4];

    // ---- Issue phase-B cls loads FIRST so they overlap phase A's mask loads ----
    float4 v[8];
    #pragma unroll
    for (int i = 0; i < 8; ++i) {
        const int b = w * 8 + i;
        v[i] = reinterpret_cast<const float4*>(cls)[b * 64 + l];
    }

    // ---- Phase A: thread pair per sample: t<64, b = t>>1, word-pair = t&1.
    // Each thread loads 8 x ulonglong2 (16B) = its sample's 8 chunk masks
    // for words {2*wp, 2*wp+1}; ORs per word, popcounts, sums. ----
    if (t < 64) {
        const int b  = t >> 1;             // 0..31
        const int wp = t & 1;              // word pair 0 -> words 0,1; 1 -> words 2,3
        const ulonglong2* base = reinterpret_cast<const ulonglong2*>(
            masks + ((unsigned)(b * CHUNKS)) * 4 + wp * 2);

        // masks[(b*CHUNKS+c)*4 + wp*2 .. +1] => base[c*2]
        ulonglong2 a0 = base[0 * 2];
        ulonglong2 a1 = base[1 * 2];
        ulonglong2 a2 = base[2 * 2];
        ulonglong2 a3 = base[3 * 2];
        ulonglong2 a4 = base[4 * 2];
        ulonglong2 a5 = base[5 * 2];
        ulonglong2 a6 = base[6 * 2];
        ulonglong2 a7 = base[7 * 2];

        // Full union per word BEFORE popcount (words are disjoint bit-ranges).
        const unsigned long long lo =
            ((a0.x | a1.x) | (a2.x | a3.x)) | ((a4.x | a5.x) | (a6.x | a7.x));
        const unsigned long long hi =
            ((a0.y | a1.y) | (a2.y | a3.y)) | ((a4.y | a5.y) | (a6.y | a7.y));

        int pc = __popcll(lo) + __popcll(hi);
        pc += __shfl_xor(pc, 1);           // add the other word-pair's count
        if (wp == 0) cnt_sh[b] = pc;
    }
    __syncthreads();

    // ---- Phase B: wave w handles samples [8w, 8w+8) (proven) ----
    float nll = 0.0f;
    #pragma unroll
    for (int i = 0; i < 8; ++i) {
        const int b = w * 8 + i;
        const float4 x = v[i];
        float m = fmaxf(fmaxf(x.x, x.y), fmaxf(x.z, x.w));
        #pragma unroll
        for (int off = 32; off > 0; off >>= 1) m = fmaxf(m, __shfl_xor(m, off));
        float e = expf(x.x - m) + expf(x.y - m) + expf(x.z - m) + expf(x.w - m);
        #pragma unroll
        for (int off = 32; off > 0; off >>= 1) e += __shfl_xor(e, off);
        const float lse = m + logf(e);

        const int cnt = cnt_sh[b];            // wave-uniform
        const int comp = cnt & 3;
        const float cand = (comp == 0) ? x.x : (comp == 1) ? x.y
                         : (comp == 2) ? x.z : x.w;
        const float target = __shfl(cand, cnt >> 2);
        nll += lse - target;
    }

    if (l == 0) partial[w] = nll;
    __syncthreads();
    if (t == 0) out[0] = (partial[0] + partial[1] + partial[2] + partial[3]) / (float)B_SAMPLES;
}

extern "C" void kernel_launch(void* const* d_in, const int* in_sizes, int n_in,
                              void* d_out, int out_size, void* d_ws, size_t ws_size,
                              hipStream_t stream) {
    const float* cls = (const float*)d_in[0];
    const int* label = (const int*)d_in[1];
    float* out = (float*)d_out;
    unsigned long long* masks = (unsigned long long*)d_ws;  // 256 * 4 * 8 = 8 KiB

    count_bitmap_kernel<<<B_SAMPLES * CHUNKS, 256, 0, stream>>>(label, masks);
    ce_kernel<<<1, 256, 0, stream>>>(cls, masks, out);
}